// Round 9
// baseline (1306.125 us; speedup 1.0000x reference)
//
#include <hip/hip_runtime.h>
#include <hip/hip_bf16.h>
#include <math.h>

#define NFEAT 500
#define KPAD  512
#define NHID  256
#define NCLS  64
#define KPOLY 10
#define DBINS 256

typedef __attribute__((ext_vector_type(8))) short short8;
typedef __attribute__((ext_vector_type(4))) float f32x4;

__device__ inline unsigned short bf16_rn(float v) {
  unsigned u = __float_as_uint(v);
  return (unsigned short)((u + 0x7FFFu + ((u >> 16) & 1u)) >> 16);
}
__device__ inline float u2f_lo(unsigned u) { return __uint_as_float(u << 16); }
__device__ inline float u2f_hi(unsigned u) { return __uint_as_float(u & 0xFFFF0000u); }
__device__ inline unsigned pack2(float a, float b) {
  return (unsigned)bf16_rn(a) | ((unsigned)bf16_rn(b) << 16);
}
__device__ inline void split2(float v, unsigned short& hi, unsigned short& lo) {
  unsigned short h = bf16_rn(v);
  float vh = __uint_as_float(((unsigned)h) << 16);
  lo = bf16_rn(v - vh);
  hi = h;
}

// ---------- weight pre-conversion into MFMA fragment layout ----------
__global__ void conv_w1f(const float* __restrict__ W1, unsigned short* __restrict__ Fh,
                         unsigned short* __restrict__ Fl) {
  int i = blockIdx.x * 256 + threadIdx.x;
  if (i >= KPAD * NHID) return;
  int kg = i >> 11, c = (i >> 3) & 255, kin = i & 7;
  int k = kg * 8 + kin;
  float v = (k < NFEAT) ? W1[c * NFEAT + k] : 0.0f;
  unsigned short h, l;
  split2(v, h, l);
  Fh[i] = h; Fl[i] = l;
}
__global__ void conv_w2f(const float* __restrict__ W2, unsigned short* __restrict__ F) {
  int i = blockIdx.x * 256 + threadIdx.x;
  if (i >= NHID * NCLS) return;
  int kg = i >> 9, c = (i >> 3) & 63, kin = i & 7;
  int k = kg * 8 + kin;
  F[i] = bf16_rn(W2[c * NHID + k]);
}

// ------------------------- CSR build -------------------------
__global__ void edge_count(const int* __restrict__ ei, int E,
                           int* __restrict__ deg, int* __restrict__ cnt) {
  int stride = gridDim.x * blockDim.x;
  for (int e = blockIdx.x * blockDim.x + threadIdx.x; e < E; e += stride) {
    int r = ei[e], c = ei[E + e];
    atomicAdd(&cnt[r], 1);
    if (r != c) atomicAdd(&deg[r], 1);
  }
}

__global__ void make_dinv(const int* __restrict__ deg, float* __restrict__ dinv, int n) {
  int i = blockIdx.x * blockDim.x + threadIdx.x;
  if (i < n) {
    int d = deg[i];
    dinv[i] = (d > 0) ? rsqrtf((float)d) : 0.0f;
  }
}

__global__ void scan_block(const int* __restrict__ cnt, int* __restrict__ rowptr,
                           int* __restrict__ bsums, int n) {
  __shared__ int s[256];
  int i = blockIdx.x * 256 + threadIdx.x;
  int v = (i < n) ? cnt[i] : 0;
  s[threadIdx.x] = v;
  __syncthreads();
  for (int off = 1; off < 256; off <<= 1) {
    int t = (threadIdx.x >= (unsigned)off) ? s[threadIdx.x - off] : 0;
    __syncthreads();
    s[threadIdx.x] += t;
    __syncthreads();
  }
  if (i < n) rowptr[i + 1] = s[threadIdx.x];
  if (threadIdx.x == 255) bsums[blockIdx.x] = s[255];
}

__global__ void scan_sums(int* __restrict__ bsums, int nb, int* __restrict__ rowptr) {
  if (threadIdx.x == 0 && blockIdx.x == 0) {
    int run = 0;
    for (int b = 0; b < nb; ++b) { int t = bsums[b]; bsums[b] = run; run += t; }
    rowptr[0] = 0;
  }
}

__global__ void scan_add(int* __restrict__ rowptr, const int* __restrict__ bsums, int n) {
  int i = blockIdx.x * 256 + threadIdx.x;
  if (i < n) rowptr[i + 1] += bsums[i >> 8];
}

__global__ void scatter_edges(const int* __restrict__ ei, int E,
                              const float* __restrict__ dinv,
                              const int* __restrict__ rowptr, int* __restrict__ cur,
                              int2* __restrict__ ecw) {
  int stride = gridDim.x * blockDim.x;
  for (int e = blockIdx.x * blockDim.x + threadIdx.x; e < E; e += stride) {
    int r = ei[e], c = ei[E + e];
    int pos = rowptr[r] + atomicAdd(&cur[r], 1);
    float wt = (r != c) ? (-dinv[r] * dinv[c]) : 0.0f;
    ecw[pos] = make_int2(c, __float_as_int(wt));
  }
}

// ---------------- degree sort (counting sort -> perm) ----------------
__global__ void deg_hist(const int* __restrict__ cnt, int* __restrict__ hist, int n) {
  int i = blockIdx.x * 256 + threadIdx.x;
  if (i < n) atomicAdd(&hist[min(cnt[i], DBINS - 1)], 1);
}
__global__ void deg_scan(const int* __restrict__ hist, int* __restrict__ base) {
  __shared__ int s[DBINS];
  int t = threadIdx.x;
  s[t] = hist[t];
  __syncthreads();
  for (int off = 1; off < DBINS; off <<= 1) {
    int v = (t >= off) ? s[t - off] : 0;
    __syncthreads();
    s[t] += v;
    __syncthreads();
  }
  base[t] = s[t] - hist[t];   // exclusive
}
__global__ void deg_scatter(const int* __restrict__ cnt, const int* __restrict__ base,
                            int* __restrict__ hcur, int* __restrict__ perm, int n) {
  int i = blockIdx.x * 256 + threadIdx.x;
  if (i < n) {
    int d = min(cnt[i], DBINS - 1);
    int pos = base[d] + atomicAdd(&hcur[d], 1);
    perm[pos] = i;
  }
}

// ------------------------- fused MLP via MFMA (bf16 hi/lo split) -------------------------
__global__ __launch_bounds__(256, 4) void mlp_mfma(
    const float* __restrict__ x, const unsigned short* __restrict__ W1Fh,
    const unsigned short* __restrict__ W1Fl, const unsigned short* __restrict__ W2F,
    unsigned short* __restrict__ hout, int n)
{
  __shared__ union {
    struct { unsigned short Ah[4][64][8], Al[4][64][8]; } g1;   // 8 KB
    struct { unsigned short A2[32][64][8]; } g2;                // 32 KB
  } u;

  const int tid = threadIdx.x;
  const int w = tid >> 6;
  const int l = tid & 63;
  const int l15 = l & 15, l4 = l >> 4;
  const int row0 = blockIdx.x * 64;

  f32x4 acc[4][4];
  const f32x4 zf = {0.0f, 0.0f, 0.0f, 0.0f};
#pragma unroll
  for (int i = 0; i < 4; ++i)
#pragma unroll
    for (int j = 0; j < 4; ++j) acc[i][j] = zf;

  for (int t = 0; t < 16; ++t) {
    const int k0 = t * 32;
    short8 bH[4], bL[4];
#pragma unroll
    for (int nf = 0; nf < 4; ++nf) {
      size_t bi = (size_t)t * 8192 + ((size_t)l4 * 256 + w * 64 + nf * 16 + l15) * 8;
      bH[nf] = *(const short8*)(W1Fh + bi);
      bL[nf] = *(const short8*)(W1Fl + bi);
    }
#pragma unroll
    for (int s = 0; s < 2; ++s) {
      int f = tid + s * 256;
      int r = f >> 3, slot = f & 7;
      int gr = row0 + r, gk = k0 + slot * 4;
      float4 v = make_float4(0.f, 0.f, 0.f, 0.f);
      if (gr < n && gk + 3 < NFEAT)
        v = *(const float4*)&x[(size_t)gr * NFEAT + gk];
      unsigned short a0, a1, a2, a3, b0, b1, b2, b3;
      split2(v.x, a0, b0); split2(v.y, a1, b1); split2(v.z, a2, b2); split2(v.w, a3, b3);
      int kg = slot >> 1, kin0 = (slot & 1) * 4;
      *(uint2*)&u.g1.Ah[kg][r][kin0] =
          make_uint2((unsigned)a0 | ((unsigned)a1 << 16), (unsigned)a2 | ((unsigned)a3 << 16));
      *(uint2*)&u.g1.Al[kg][r][kin0] =
          make_uint2((unsigned)b0 | ((unsigned)b1 << 16), (unsigned)b2 | ((unsigned)b3 << 16));
    }
    __syncthreads();

#pragma unroll
    for (int mf = 0; mf < 4; ++mf) {
      short8 aH = *(const short8*)&u.g1.Ah[l4][mf * 16 + l15][0];
      short8 aL = *(const short8*)&u.g1.Al[l4][mf * 16 + l15][0];
#pragma unroll
      for (int nf = 0; nf < 4; ++nf) {
        acc[mf][nf] = __builtin_amdgcn_mfma_f32_16x16x32_bf16(aH, bH[nf], acc[mf][nf], 0, 0, 0);
        acc[mf][nf] = __builtin_amdgcn_mfma_f32_16x16x32_bf16(aH, bL[nf], acc[mf][nf], 0, 0, 0);
        acc[mf][nf] = __builtin_amdgcn_mfma_f32_16x16x32_bf16(aL, bH[nf], acc[mf][nf], 0, 0, 0);
      }
    }
    __syncthreads();
  }

#pragma unroll
  for (int mf = 0; mf < 4; ++mf)
#pragma unroll
    for (int nf = 0; nf < 4; ++nf) {
      int col = w * 64 + nf * 16 + l15;
      int kg = col >> 3, kin = col & 7;
#pragma unroll
      for (int j = 0; j < 4; ++j) {
        float vv = fmaxf(acc[mf][nf][j], 0.0f);
        u.g2.A2[kg][mf * 16 + l4 * 4 + j][kin] = bf16_rn(vv);
      }
    }
  __syncthreads();

  f32x4 acc2[4];
#pragma unroll
  for (int i = 0; i < 4; ++i) acc2[i] = zf;
#pragma unroll
  for (int ks = 0; ks < 8; ++ks) {
    short8 a2 = *(const short8*)&u.g2.A2[ks * 4 + l4][w * 16 + l15][0];
#pragma unroll
    for (int nf2 = 0; nf2 < 4; ++nf2) {
      size_t bi = ((size_t)(ks * 4 + l4) * 64 + nf2 * 16 + l15) * 8;
      short8 b2 = *(const short8*)(W2F + bi);
      acc2[nf2] = __builtin_amdgcn_mfma_f32_16x16x32_bf16(a2, b2, acc2[nf2], 0, 0, 0);
    }
  }
#pragma unroll
  for (int nf2 = 0; nf2 < 4; ++nf2)
#pragma unroll
    for (int j = 0; j < 4; ++j) {
      int r = row0 + w * 16 + l4 * 4 + j;
      if (r < n) hout[(size_t)r * NCLS + nf2 * 16 + l15] = bf16_rn(acc2[nf2][j]);
    }
}

// ---------------- SpMM: one row per 8-lane group, 4-edge unrolled gather ----------------
__device__ inline void acc8(float s[8], float w, uint4 h) {
  s[0] = fmaf(w, u2f_lo(h.x), s[0]); s[1] = fmaf(w, u2f_hi(h.x), s[1]);
  s[2] = fmaf(w, u2f_lo(h.y), s[2]); s[3] = fmaf(w, u2f_hi(h.y), s[3]);
  s[4] = fmaf(w, u2f_lo(h.z), s[4]); s[5] = fmaf(w, u2f_hi(h.z), s[5]);
  s[6] = fmaf(w, u2f_lo(h.w), s[6]); s[7] = fmaf(w, u2f_hi(h.w), s[7]);
}

__device__ inline void gather_one(const int* __restrict__ rowptr,
                                  const int2* __restrict__ ecw,
                                  const unsigned short* __restrict__ src,
                                  int row, int p, float s[8]) {
#pragma unroll
  for (int i = 0; i < 8; ++i) s[i] = 0.0f;
  int e = rowptr[row], e1 = rowptr[row + 1];
  const unsigned short* b = src + (p << 3);
  while (e + 4 <= e1) {
    int2 t0 = ecw[e], t1 = ecw[e + 1], t2 = ecw[e + 2], t3 = ecw[e + 3];
    uint4 h0 = *(const uint4*)(b + (((size_t)t0.x) << 6));
    uint4 h1 = *(const uint4*)(b + (((size_t)t1.x) << 6));
    uint4 h2 = *(const uint4*)(b + (((size_t)t2.x) << 6));
    uint4 h3 = *(const uint4*)(b + (((size_t)t3.x) << 6));
    acc8(s, __int_as_float(t0.y), h0);
    acc8(s, __int_as_float(t1.y), h1);
    acc8(s, __int_as_float(t2.y), h2);
    acc8(s, __int_as_float(t3.y), h3);
    e += 4;
  }
  while (e < e1) {
    int2 t = ecw[e];
    uint4 h0 = *(const uint4*)(b + (((size_t)t.x) << 6));
    acc8(s, __int_as_float(t.y), h0);
    ++e;
  }
}

__global__ void spmm_first(const int* __restrict__ rowptr, const int* __restrict__ perm,
                           const int2* __restrict__ ecw,
                           const unsigned short* __restrict__ h, unsigned short* __restrict__ tx1,
                           float* __restrict__ acc, const float* __restrict__ cw, int n) {
  int wv = (blockIdx.x * blockDim.x + threadIdx.x) >> 6;
  int lane = threadIdx.x & 63;
  int p = lane & 7, g = lane >> 3;
  int idx = wv * 8 + g;
  if (idx >= n) return;
  int row = perm[idx];
  float s[8];
  gather_one(rowptr, ecw, h, row, p, s);
  size_t base = (size_t)row * NCLS + (p << 3);
  uint4 hv = *(const uint4*)(h + base);
  float c0 = cw[0], c1 = cw[1];
  float4 a0, a1;
  a0.x = c0 * u2f_lo(hv.x) + c1 * s[0]; a0.y = c0 * u2f_hi(hv.x) + c1 * s[1];
  a0.z = c0 * u2f_lo(hv.y) + c1 * s[2]; a0.w = c0 * u2f_hi(hv.y) + c1 * s[3];
  a1.x = c0 * u2f_lo(hv.z) + c1 * s[4]; a1.y = c0 * u2f_hi(hv.z) + c1 * s[5];
  a1.z = c0 * u2f_lo(hv.w) + c1 * s[6]; a1.w = c0 * u2f_hi(hv.w) + c1 * s[7];
  *(float4*)(acc + base) = a0;
  *(float4*)(acc + base + 4) = a1;
  uint4 tw;
  tw.x = pack2(s[0], s[1]); tw.y = pack2(s[2], s[3]);
  tw.z = pack2(s[4], s[5]); tw.w = pack2(s[6], s[7]);
  *(uint4*)(tx1 + base) = tw;
}

__global__ void spmm_step(const int* __restrict__ rowptr, const int* __restrict__ perm,
                          const int2* __restrict__ ecw,
                          const unsigned short* __restrict__ curb,
                          const unsigned short* __restrict__ prevb,
                          unsigned short* __restrict__ nextb, float* __restrict__ acc,
                          const float* __restrict__ cw, int k, int last, int n) {
  int wv = (blockIdx.x * blockDim.x + threadIdx.x) >> 6;
  int lane = threadIdx.x & 63;
  int p = lane & 7, g = lane >> 3;
  int idx = wv * 8 + g;
  if (idx >= n) return;
  int row = perm[idx];
  float s[8];
  gather_one(rowptr, ecw, curb, row, p, s);
  size_t base = (size_t)row * NCLS + (p << 3);
  uint4 pv = *(const uint4*)(prevb + base);
  float t[8];
  t[0] = 2.0f * s[0] - u2f_lo(pv.x); t[1] = 2.0f * s[1] - u2f_hi(pv.x);
  t[2] = 2.0f * s[2] - u2f_lo(pv.y); t[3] = 2.0f * s[3] - u2f_hi(pv.y);
  t[4] = 2.0f * s[4] - u2f_lo(pv.z); t[5] = 2.0f * s[5] - u2f_hi(pv.z);
  t[6] = 2.0f * s[6] - u2f_lo(pv.w); t[7] = 2.0f * s[7] - u2f_hi(pv.w);
  float ck = cw[k];
  if (!last) {
    uint4 nw;
    nw.x = pack2(t[0], t[1]); nw.y = pack2(t[2], t[3]);
    nw.z = pack2(t[4], t[5]); nw.w = pack2(t[6], t[7]);
    *(uint4*)(nextb + base) = nw;
    float4 a0 = *(const float4*)(acc + base);
    float4 a1 = *(const float4*)(acc + base + 4);
    a0.x = fmaf(ck, t[0], a0.x); a0.y = fmaf(ck, t[1], a0.y);
    a0.z = fmaf(ck, t[2], a0.z); a0.w = fmaf(ck, t[3], a0.w);
    a1.x = fmaf(ck, t[4], a1.x); a1.y = fmaf(ck, t[5], a1.y);
    a1.z = fmaf(ck, t[6], a1.z); a1.w = fmaf(ck, t[7], a1.w);
    *(float4*)(acc + base) = a0;
    *(float4*)(acc + base + 4) = a1;
  } else {
    float4 a0 = *(const float4*)(acc + base);
    float4 a1 = *(const float4*)(acc + base + 4);
    float v[8];
    v[0] = fmaf(ck, t[0], a0.x); v[1] = fmaf(ck, t[1], a0.y);
    v[2] = fmaf(ck, t[2], a0.z); v[3] = fmaf(ck, t[3], a0.w);
    v[4] = fmaf(ck, t[4], a1.x); v[5] = fmaf(ck, t[5], a1.y);
    v[6] = fmaf(ck, t[6], a1.z); v[7] = fmaf(ck, t[7], a1.w);
    float m = v[0];
#pragma unroll
    for (int i = 1; i < 8; ++i) m = fmaxf(m, v[i]);
    m = fmaxf(m, __shfl_xor(m, 1, 64));
    m = fmaxf(m, __shfl_xor(m, 2, 64));
    m = fmaxf(m, __shfl_xor(m, 4, 64));
    float ss = 0.0f;
#pragma unroll
    for (int i = 0; i < 8; ++i) ss += expf(v[i] - m);
    ss += __shfl_xor(ss, 1, 64);
    ss += __shfl_xor(ss, 2, 64);
    ss += __shfl_xor(ss, 4, 64);
    float lg = m + logf(ss);
    float4 o0, o1;
    o0.x = v[0] - lg; o0.y = v[1] - lg; o0.z = v[2] - lg; o0.w = v[3] - lg;
    o1.x = v[4] - lg; o1.y = v[5] - lg; o1.z = v[6] - lg; o1.w = v[7] - lg;
    *(float4*)(acc + base) = o0;
    *(float4*)(acc + base + 4) = o1;
  }
}

// ------------------------- launch -------------------------
extern "C" void kernel_launch(void* const* d_in, const int* in_sizes, int n_in,
                              void* d_out, int out_size, void* d_ws, size_t ws_size,
                              hipStream_t stream) {
  const float* x  = (const float*)d_in[0];
  const int*   ei = (const int*)d_in[1];
  const float* W1 = (const float*)d_in[2];
  const float* W2 = (const float*)d_in[3];
  const float* cw = (const float*)d_in[4];
  float* out = (float*)d_out;

  const int n = in_sizes[0] / NFEAT;     // 100000
  const int E = in_sizes[1] / 2;         // 1600000

  size_t off = 0;
  auto alloc = [&](size_t bytes) { size_t o = off; off += (bytes + 255) & ~(size_t)255; return o; };
  char* w = (char*)d_ws;
  size_t o_deg   = alloc((size_t)n * 4);
  size_t o_cnt   = alloc((size_t)n * 4);
  size_t o_cur   = alloc((size_t)n * 4);
  size_t o_hist  = alloc(DBINS * 4);
  size_t o_hcur  = alloc(DBINS * 4);
  size_t o_dinv  = alloc((size_t)n * 4);      // memset region ends here
  size_t o_rp    = alloc((size_t)(n + 1) * 4);
  size_t o_bs    = alloc(4096 * 4);
  size_t o_hbase = alloc(DBINS * 4);
  size_t o_perm  = alloc((size_t)n * 4);
  size_t o_w1fh  = alloc((size_t)KPAD * NHID * 2);
  size_t o_w1fl  = alloc((size_t)KPAD * NHID * 2);
  size_t o_w2f   = alloc((size_t)NHID * NCLS * 2);
  size_t o_ecw   = alloc((size_t)E * 8);
  size_t o_bufH  = alloc((size_t)n * NCLS * 2);
  size_t o_bufA  = alloc((size_t)n * NCLS * 2);
  size_t o_bufB  = alloc((size_t)n * NCLS * 2);

  int*   deg    = (int*)(w + o_deg);
  int*   cnt    = (int*)(w + o_cnt);
  int*   curi   = (int*)(w + o_cur);
  int*   hist   = (int*)(w + o_hist);
  int*   hcur   = (int*)(w + o_hcur);
  float* dinv   = (float*)(w + o_dinv);
  int*   rowptr = (int*)(w + o_rp);
  int*   bsums  = (int*)(w + o_bs);
  int*   hbase  = (int*)(w + o_hbase);
  int*   perm   = (int*)(w + o_perm);
  unsigned short* W1Fh = (unsigned short*)(w + o_w1fh);
  unsigned short* W1Fl = (unsigned short*)(w + o_w1fl);
  unsigned short* W2F  = (unsigned short*)(w + o_w2f);
  int2*  ecw    = (int2*)(w + o_ecw);
  unsigned short* bufH = (unsigned short*)(w + o_bufH);
  unsigned short* bufA = (unsigned short*)(w + o_bufA);
  unsigned short* bufB = (unsigned short*)(w + o_bufB);

  hipMemsetAsync(w + o_deg, 0, o_dinv - o_deg, stream);

  const int nb = (n + 255) / 256;

  conv_w1f<<<(KPAD * NHID + 255) / 256, 256, 0, stream>>>(W1, W1Fh, W1Fl);
  conv_w2f<<<(NHID * NCLS + 255) / 256, 256, 0, stream>>>(W2, W2F);

  edge_count<<<1024, 256, 0, stream>>>(ei, E, deg, cnt);
  make_dinv<<<nb, 256, 0, stream>>>(deg, dinv, n);
  scan_block<<<nb, 256, 0, stream>>>(cnt, rowptr, bsums, n);
  scan_sums<<<1, 1, 0, stream>>>(bsums, nb, rowptr);
  scan_add<<<nb, 256, 0, stream>>>(rowptr, bsums, n);
  scatter_edges<<<1024, 256, 0, stream>>>(ei, E, dinv, rowptr, curi, ecw);

  // degree sort -> perm
  deg_hist<<<nb, 256, 0, stream>>>(cnt, hist, n);
  deg_scan<<<1, DBINS, 0, stream>>>(hist, hbase);
  deg_scatter<<<nb, 256, 0, stream>>>(cnt, hbase, hcur, perm, n);

  mlp_mfma<<<(n + 63) / 64, 256, 0, stream>>>(x, W1Fh, W1Fl, W2F, bufH, n);

  // 8 rows per wave, 4 waves per block
  const int waves = (n + 7) / 8;
  const int spmm_blocks = (waves + 3) / 4;
  spmm_first<<<spmm_blocks, 256, 0, stream>>>(rowptr, perm, ecw, bufH, bufA, out, cw, n);

  unsigned short* P = bufH;
  unsigned short* C = bufA;
  unsigned short* N = bufB;
  for (int k = 2; k <= KPOLY; ++k) {
    spmm_step<<<spmm_blocks, 256, 0, stream>>>(rowptr, perm, ecw, C, P, N, out, cw, k,
                                               (k == KPOLY) ? 1 : 0, n);
    unsigned short* t = P; P = C; C = N; N = t;
  }
}

// Round 10
// 815.552 us; speedup vs baseline: 1.6015x; 1.6015x over previous
//
#include <hip/hip_runtime.h>
#include <hip/hip_bf16.h>
#include <math.h>

#define NFEAT 500
#define KPAD  512
#define NHID  256
#define NCLS  64
#define KPOLY 10

typedef __attribute__((ext_vector_type(8))) short short8;
typedef __attribute__((ext_vector_type(4))) float f32x4;

__device__ inline unsigned short bf16_rn(float v) {
  unsigned u = __float_as_uint(v);
  return (unsigned short)((u + 0x7FFFu + ((u >> 16) & 1u)) >> 16);
}
__device__ inline float u2f_lo(unsigned u) { return __uint_as_float(u << 16); }
__device__ inline float u2f_hi(unsigned u) { return __uint_as_float(u & 0xFFFF0000u); }
__device__ inline unsigned pack2(float a, float b) {
  return (unsigned)bf16_rn(a) | ((unsigned)bf16_rn(b) << 16);
}
__device__ inline void split2(float v, unsigned short& hi, unsigned short& lo) {
  unsigned short h = bf16_rn(v);
  float vh = __uint_as_float(((unsigned)h) << 16);
  lo = bf16_rn(v - vh);
  hi = h;
}

// ---------- weight pre-conversion into MFMA fragment layout ----------
__global__ void conv_w1f(const float* __restrict__ W1, unsigned short* __restrict__ Fh,
                         unsigned short* __restrict__ Fl) {
  int i = blockIdx.x * 256 + threadIdx.x;
  if (i >= KPAD * NHID) return;
  int kg = i >> 11, c = (i >> 3) & 255, kin = i & 7;
  int k = kg * 8 + kin;
  float v = (k < NFEAT) ? W1[c * NFEAT + k] : 0.0f;
  unsigned short h, l;
  split2(v, h, l);
  Fh[i] = h; Fl[i] = l;
}
__global__ void conv_w2f(const float* __restrict__ W2, unsigned short* __restrict__ F) {
  int i = blockIdx.x * 256 + threadIdx.x;
  if (i >= NHID * NCLS) return;
  int kg = i >> 9, c = (i >> 3) & 63, kin = i & 7;
  int k = kg * 8 + kin;
  F[i] = bf16_rn(W2[c * NHID + k]);
}

// ------------------------- CSR build -------------------------
__global__ void edge_count(const int* __restrict__ ei, int E,
                           int* __restrict__ deg, int* __restrict__ cnt) {
  int stride = gridDim.x * blockDim.x;
  for (int e = blockIdx.x * blockDim.x + threadIdx.x; e < E; e += stride) {
    int r = ei[e], c = ei[E + e];
    atomicAdd(&cnt[r], 1);
    if (r != c) atomicAdd(&deg[r], 1);
  }
}

__global__ void make_dinv(const int* __restrict__ deg, float* __restrict__ dinv, int n) {
  int i = blockIdx.x * blockDim.x + threadIdx.x;
  if (i < n) {
    int d = deg[i];
    dinv[i] = (d > 0) ? rsqrtf((float)d) : 0.0f;
  }
}

__global__ void scan_block(const int* __restrict__ cnt, int* __restrict__ rowptr,
                           int* __restrict__ bsums, int n) {
  __shared__ int s[256];
  int i = blockIdx.x * 256 + threadIdx.x;
  int v = (i < n) ? cnt[i] : 0;
  s[threadIdx.x] = v;
  __syncthreads();
  for (int off = 1; off < 256; off <<= 1) {
    int t = (threadIdx.x >= (unsigned)off) ? s[threadIdx.x - off] : 0;
    __syncthreads();
    s[threadIdx.x] += t;
    __syncthreads();
  }
  if (i < n) rowptr[i + 1] = s[threadIdx.x];
  if (threadIdx.x == 255) bsums[blockIdx.x] = s[255];
}

__global__ void scan_sums(int* __restrict__ bsums, int nb, int* __restrict__ rowptr) {
  if (threadIdx.x == 0 && blockIdx.x == 0) {
    int run = 0;
    for (int b = 0; b < nb; ++b) { int t = bsums[b]; bsums[b] = run; run += t; }
    rowptr[0] = 0;
  }
}

__global__ void scan_add(int* __restrict__ rowptr, const int* __restrict__ bsums, int n) {
  int i = blockIdx.x * 256 + threadIdx.x;
  if (i < n) rowptr[i + 1] += bsums[i >> 8];
}

__global__ void scatter_edges(const int* __restrict__ ei, int E,
                              const float* __restrict__ dinv,
                              const int* __restrict__ rowptr, int* __restrict__ cur,
                              int2* __restrict__ ecw) {
  int stride = gridDim.x * blockDim.x;
  for (int e = blockIdx.x * blockDim.x + threadIdx.x; e < E; e += stride) {
    int r = ei[e], c = ei[E + e];
    int pos = rowptr[r] + atomicAdd(&cur[r], 1);
    float wt = (r != c) ? (-dinv[r] * dinv[c]) : 0.0f;
    ecw[pos] = make_int2(c, __float_as_int(wt));
  }
}

// ------------------------- fused MLP via MFMA (bf16 hi/lo split) -------------------------
__global__ __launch_bounds__(256, 4) void mlp_mfma(
    const float* __restrict__ x, const unsigned short* __restrict__ W1Fh,
    const unsigned short* __restrict__ W1Fl, const unsigned short* __restrict__ W2F,
    unsigned short* __restrict__ hout, int n)
{
  __shared__ union {
    struct { unsigned short Ah[4][64][8], Al[4][64][8]; } g1;   // 8 KB
    struct { unsigned short A2[32][64][8]; } g2;                // 32 KB
  } u;

  const int tid = threadIdx.x;
  const int w = tid >> 6;
  const int l = tid & 63;
  const int l15 = l & 15, l4 = l >> 4;
  const int row0 = blockIdx.x * 64;

  f32x4 acc[4][4];
  const f32x4 zf = {0.0f, 0.0f, 0.0f, 0.0f};
#pragma unroll
  for (int i = 0; i < 4; ++i)
#pragma unroll
    for (int j = 0; j < 4; ++j) acc[i][j] = zf;

  for (int t = 0; t < 16; ++t) {
    const int k0 = t * 32;
    short8 bH[4], bL[4];
#pragma unroll
    for (int nf = 0; nf < 4; ++nf) {
      size_t bi = (size_t)t * 8192 + ((size_t)l4 * 256 + w * 64 + nf * 16 + l15) * 8;
      bH[nf] = *(const short8*)(W1Fh + bi);
      bL[nf] = *(const short8*)(W1Fl + bi);
    }
#pragma unroll
    for (int s = 0; s < 2; ++s) {
      int f = tid + s * 256;
      int r = f >> 3, slot = f & 7;
      int gr = row0 + r, gk = k0 + slot * 4;
      float4 v = make_float4(0.f, 0.f, 0.f, 0.f);
      if (gr < n && gk + 3 < NFEAT)
        v = *(const float4*)&x[(size_t)gr * NFEAT + gk];
      unsigned short a0, a1, a2, a3, b0, b1, b2, b3;
      split2(v.x, a0, b0); split2(v.y, a1, b1); split2(v.z, a2, b2); split2(v.w, a3, b3);
      int kg = slot >> 1, kin0 = (slot & 1) * 4;
      *(uint2*)&u.g1.Ah[kg][r][kin0] =
          make_uint2((unsigned)a0 | ((unsigned)a1 << 16), (unsigned)a2 | ((unsigned)a3 << 16));
      *(uint2*)&u.g1.Al[kg][r][kin0] =
          make_uint2((unsigned)b0 | ((unsigned)b1 << 16), (unsigned)b2 | ((unsigned)b3 << 16));
    }
    __syncthreads();

#pragma unroll
    for (int mf = 0; mf < 4; ++mf) {
      short8 aH = *(const short8*)&u.g1.Ah[l4][mf * 16 + l15][0];
      short8 aL = *(const short8*)&u.g1.Al[l4][mf * 16 + l15][0];
#pragma unroll
      for (int nf = 0; nf < 4; ++nf) {
        acc[mf][nf] = __builtin_amdgcn_mfma_f32_16x16x32_bf16(aH, bH[nf], acc[mf][nf], 0, 0, 0);
        acc[mf][nf] = __builtin_amdgcn_mfma_f32_16x16x32_bf16(aH, bL[nf], acc[mf][nf], 0, 0, 0);
        acc[mf][nf] = __builtin_amdgcn_mfma_f32_16x16x32_bf16(aL, bH[nf], acc[mf][nf], 0, 0, 0);
      }
    }
    __syncthreads();
  }

#pragma unroll
  for (int mf = 0; mf < 4; ++mf)
#pragma unroll
    for (int nf = 0; nf < 4; ++nf) {
      int col = w * 64 + nf * 16 + l15;
      int kg = col >> 3, kin = col & 7;
#pragma unroll
      for (int j = 0; j < 4; ++j) {
        float vv = fmaxf(acc[mf][nf][j], 0.0f);
        u.g2.A2[kg][mf * 16 + l4 * 4 + j][kin] = bf16_rn(vv);
      }
    }
  __syncthreads();

  f32x4 acc2[4];
#pragma unroll
  for (int i = 0; i < 4; ++i) acc2[i] = zf;
#pragma unroll
  for (int ks = 0; ks < 8; ++ks) {
    short8 a2 = *(const short8*)&u.g2.A2[ks * 4 + l4][w * 16 + l15][0];
#pragma unroll
    for (int nf2 = 0; nf2 < 4; ++nf2) {
      size_t bi = ((size_t)(ks * 4 + l4) * 64 + nf2 * 16 + l15) * 8;
      short8 b2 = *(const short8*)(W2F + bi);
      acc2[nf2] = __builtin_amdgcn_mfma_f32_16x16x32_bf16(a2, b2, acc2[nf2], 0, 0, 0);
    }
  }
#pragma unroll
  for (int nf2 = 0; nf2 < 4; ++nf2)
#pragma unroll
    for (int j = 0; j < 4; ++j) {
      int r = row0 + w * 16 + l4 * 4 + j;
      if (r < n) hout[(size_t)r * NCLS + nf2 * 16 + l15] = bf16_rn(acc2[nf2][j]);
    }
}

// ---------------- SpMM: 2 rows per wave, 8 lanes/edge, interleaved gather streams --------
__device__ inline void acc8(float s[8], float w, uint4 h) {
  s[0] = fmaf(w, u2f_lo(h.x), s[0]); s[1] = fmaf(w, u2f_hi(h.x), s[1]);
  s[2] = fmaf(w, u2f_lo(h.y), s[2]); s[3] = fmaf(w, u2f_hi(h.y), s[3]);
  s[4] = fmaf(w, u2f_lo(h.z), s[4]); s[5] = fmaf(w, u2f_hi(h.z), s[5]);
  s[6] = fmaf(w, u2f_lo(h.w), s[6]); s[7] = fmaf(w, u2f_hi(h.w), s[7]);
}

// Gathers Laplacian-weighted sums for TWO rows simultaneously.
// lane = g*8+p. Per iteration: 16 edges of row A + 16 edges of row B -> 4 gathers in flight.
__device__ inline void gather_two(const int* __restrict__ rowptr,
                                  const int2* __restrict__ ecw,
                                  const unsigned short* __restrict__ src,
                                  int rowA, int rowB, bool hasB, int p, int g,
                                  float sA[8], float sB[8]) {
#pragma unroll
  for (int i = 0; i < 8; ++i) { sA[i] = 0.0f; sB[i] = 0.0f; }
  int e0a = rowptr[rowA], e1a = rowptr[rowA + 1];
  int e0b = 0, e1b = 0;
  if (hasB) { e0b = rowptr[rowB]; e1b = rowptr[rowB + 1]; }
  int ita = (e1a - e0a + 15) >> 4;
  int itb = (e1b - e0b + 15) >> 4;
  int itm = (ita > itb) ? ita : itb;
  const unsigned short* bp = src + (p << 3);
  for (int it = 0; it < itm; ++it) {
    int ba = e0a + it * 16, bb = e0b + it * 16;
    int eeA0 = ba + g,     eeA1 = ba + 8 + g;
    int eeB0 = bb + g,     eeB1 = bb + 8 + g;
    int iA0 = max(min(eeA0, e1a - 1), 0);
    int iA1 = max(min(eeA1, e1a - 1), 0);
    int iB0 = max(min(eeB0, e1b - 1), 0);
    int iB1 = max(min(eeB1, e1b - 1), 0);
    int2 tA0 = ecw[iA0];
    int2 tA1 = ecw[iA1];
    int2 tB0 = ecw[iB0];
    int2 tB1 = ecw[iB1];
    uint4 hA0 = *(const uint4*)(bp + (((size_t)tA0.x) << 6));
    uint4 hA1 = *(const uint4*)(bp + (((size_t)tA1.x) << 6));
    uint4 hB0 = *(const uint4*)(bp + (((size_t)tB0.x) << 6));
    uint4 hB1 = *(const uint4*)(bp + (((size_t)tB1.x) << 6));
    float wA0 = (eeA0 < e1a) ? __int_as_float(tA0.y) : 0.0f;
    float wA1 = (eeA1 < e1a) ? __int_as_float(tA1.y) : 0.0f;
    float wB0 = (eeB0 < e1b) ? __int_as_float(tB0.y) : 0.0f;
    float wB1 = (eeB1 < e1b) ? __int_as_float(tB1.y) : 0.0f;
    acc8(sA, wA0, hA0);
    acc8(sA, wA1, hA1);
    acc8(sB, wB0, hB0);
    acc8(sB, wB1, hB1);
  }
#pragma unroll
  for (int i = 0; i < 8; ++i) {
    sA[i] += __shfl_xor(sA[i], 8, 64);
    sA[i] += __shfl_xor(sA[i], 16, 64);
    sA[i] += __shfl_xor(sA[i], 32, 64);
    sB[i] += __shfl_xor(sB[i], 8, 64);
    sB[i] += __shfl_xor(sB[i], 16, 64);
    sB[i] += __shfl_xor(sB[i], 32, 64);
  }
}

__global__ void spmm_first(const int* __restrict__ rowptr, const int2* __restrict__ ecw,
                           const unsigned short* __restrict__ h, unsigned short* __restrict__ tx1,
                           float* __restrict__ acc, const float* __restrict__ cw, int n) {
  int wv = (blockIdx.x * blockDim.x + threadIdx.x) >> 6;
  int lane = threadIdx.x & 63;
  int p = lane & 7, g = lane >> 3;
  int rowA = wv * 2;
  if (rowA >= n) return;
  int rowB = rowA + 1;
  bool hasB = rowB < n;
  float sA[8], sB[8];
  gather_two(rowptr, ecw, h, rowA, hasB ? rowB : rowA, hasB, p, g, sA, sB);
  float c0 = cw[0], c1 = cw[1];
  if (g == 0) {
    size_t base = (size_t)rowA * NCLS + (p << 3);
    uint4 hv = *(const uint4*)(h + base);
    float4 a0, a1;
    a0.x = c0 * u2f_lo(hv.x) + c1 * sA[0]; a0.y = c0 * u2f_hi(hv.x) + c1 * sA[1];
    a0.z = c0 * u2f_lo(hv.y) + c1 * sA[2]; a0.w = c0 * u2f_hi(hv.y) + c1 * sA[3];
    a1.x = c0 * u2f_lo(hv.z) + c1 * sA[4]; a1.y = c0 * u2f_hi(hv.z) + c1 * sA[5];
    a1.z = c0 * u2f_lo(hv.w) + c1 * sA[6]; a1.w = c0 * u2f_hi(hv.w) + c1 * sA[7];
    *(float4*)(acc + base) = a0;
    *(float4*)(acc + base + 4) = a1;
    uint4 tw;
    tw.x = pack2(sA[0], sA[1]); tw.y = pack2(sA[2], sA[3]);
    tw.z = pack2(sA[4], sA[5]); tw.w = pack2(sA[6], sA[7]);
    *(uint4*)(tx1 + base) = tw;
  }
  if (g == 1 && hasB) {
    size_t base = (size_t)rowB * NCLS + (p << 3);
    uint4 hv = *(const uint4*)(h + base);
    float4 a0, a1;
    a0.x = c0 * u2f_lo(hv.x) + c1 * sB[0]; a0.y = c0 * u2f_hi(hv.x) + c1 * sB[1];
    a0.z = c0 * u2f_lo(hv.y) + c1 * sB[2]; a0.w = c0 * u2f_hi(hv.y) + c1 * sB[3];
    a1.x = c0 * u2f_lo(hv.z) + c1 * sB[4]; a1.y = c0 * u2f_hi(hv.z) + c1 * sB[5];
    a1.z = c0 * u2f_lo(hv.w) + c1 * sB[6]; a1.w = c0 * u2f_hi(hv.w) + c1 * sB[7];
    *(float4*)(acc + base) = a0;
    *(float4*)(acc + base + 4) = a1;
    uint4 tw;
    tw.x = pack2(sB[0], sB[1]); tw.y = pack2(sB[2], sB[3]);
    tw.z = pack2(sB[4], sB[5]); tw.w = pack2(sB[6], sB[7]);
    *(uint4*)(tx1 + base) = tw;
  }
}

__device__ inline void step_epilogue(const unsigned short* __restrict__ prevb,
                                     unsigned short* __restrict__ nextb,
                                     float* __restrict__ acc, float ck, int last,
                                     size_t base, const float s[8]) {
  uint4 pv = *(const uint4*)(prevb + base);
  float t[8];
  t[0] = 2.0f * s[0] - u2f_lo(pv.x); t[1] = 2.0f * s[1] - u2f_hi(pv.x);
  t[2] = 2.0f * s[2] - u2f_lo(pv.y); t[3] = 2.0f * s[3] - u2f_hi(pv.y);
  t[4] = 2.0f * s[4] - u2f_lo(pv.z); t[5] = 2.0f * s[5] - u2f_hi(pv.z);
  t[6] = 2.0f * s[6] - u2f_lo(pv.w); t[7] = 2.0f * s[7] - u2f_hi(pv.w);
  if (!last) {
    uint4 nw;
    nw.x = pack2(t[0], t[1]); nw.y = pack2(t[2], t[3]);
    nw.z = pack2(t[4], t[5]); nw.w = pack2(t[6], t[7]);
    *(uint4*)(nextb + base) = nw;
    float4 a0 = *(const float4*)(acc + base);
    float4 a1 = *(const float4*)(acc + base + 4);
    a0.x = fmaf(ck, t[0], a0.x); a0.y = fmaf(ck, t[1], a0.y);
    a0.z = fmaf(ck, t[2], a0.z); a0.w = fmaf(ck, t[3], a0.w);
    a1.x = fmaf(ck, t[4], a1.x); a1.y = fmaf(ck, t[5], a1.y);
    a1.z = fmaf(ck, t[6], a1.z); a1.w = fmaf(ck, t[7], a1.w);
    *(float4*)(acc + base) = a0;
    *(float4*)(acc + base + 4) = a1;
  } else {
    float4 a0 = *(const float4*)(acc + base);
    float4 a1 = *(const float4*)(acc + base + 4);
    float v[8];
    v[0] = fmaf(ck, t[0], a0.x); v[1] = fmaf(ck, t[1], a0.y);
    v[2] = fmaf(ck, t[2], a0.z); v[3] = fmaf(ck, t[3], a0.w);
    v[4] = fmaf(ck, t[4], a1.x); v[5] = fmaf(ck, t[5], a1.y);
    v[6] = fmaf(ck, t[6], a1.z); v[7] = fmaf(ck, t[7], a1.w);
    float m = v[0];
#pragma unroll
    for (int i = 1; i < 8; ++i) m = fmaxf(m, v[i]);
    m = fmaxf(m, __shfl_xor(m, 1, 64));
    m = fmaxf(m, __shfl_xor(m, 2, 64));
    m = fmaxf(m, __shfl_xor(m, 4, 64));
    float ss = 0.0f;
#pragma unroll
    for (int i = 0; i < 8; ++i) ss += expf(v[i] - m);
    ss += __shfl_xor(ss, 1, 64);
    ss += __shfl_xor(ss, 2, 64);
    ss += __shfl_xor(ss, 4, 64);
    float lg = m + logf(ss);
    float4 o0, o1;
    o0.x = v[0] - lg; o0.y = v[1] - lg; o0.z = v[2] - lg; o0.w = v[3] - lg;
    o1.x = v[4] - lg; o1.y = v[5] - lg; o1.z = v[6] - lg; o1.w = v[7] - lg;
    *(float4*)(acc + base) = o0;
    *(float4*)(acc + base + 4) = o1;
  }
}

__global__ void spmm_step(const int* __restrict__ rowptr, const int2* __restrict__ ecw,
                          const unsigned short* __restrict__ curb,
                          const unsigned short* __restrict__ prevb,
                          unsigned short* __restrict__ nextb, float* __restrict__ acc,
                          const float* __restrict__ cw, int k, int last, int n) {
  int wv = (blockIdx.x * blockDim.x + threadIdx.x) >> 6;
  int lane = threadIdx.x & 63;
  int p = lane & 7, g = lane >> 3;
  int rowA = wv * 2;
  if (rowA >= n) return;
  int rowB = rowA + 1;
  bool hasB = rowB < n;
  float sA[8], sB[8];
  gather_two(rowptr, ecw, curb, rowA, hasB ? rowB : rowA, hasB, p, g, sA, sB);
  float ck = cw[k];
  if (g == 0)
    step_epilogue(prevb, nextb, acc, ck, last, (size_t)rowA * NCLS + (p << 3), sA);
  if (g == 1 && hasB)
    step_epilogue(prevb, nextb, acc, ck, last, (size_t)rowB * NCLS + (p << 3), sB);
}

// ------------------------- launch -------------------------
extern "C" void kernel_launch(void* const* d_in, const int* in_sizes, int n_in,
                              void* d_out, int out_size, void* d_ws, size_t ws_size,
                              hipStream_t stream) {
  const float* x  = (const float*)d_in[0];
  const int*   ei = (const int*)d_in[1];
  const float* W1 = (const float*)d_in[2];
  const float* W2 = (const float*)d_in[3];
  const float* cw = (const float*)d_in[4];
  float* out = (float*)d_out;

  const int n = in_sizes[0] / NFEAT;     // 100000
  const int E = in_sizes[1] / 2;         // 1600000

  size_t off = 0;
  auto alloc = [&](size_t bytes) { size_t o = off; off += (bytes + 255) & ~(size_t)255; return o; };
  char* w = (char*)d_ws;
  size_t o_deg   = alloc((size_t)n * 4);
  size_t o_cnt   = alloc((size_t)n * 4);
  size_t o_cur   = alloc((size_t)n * 4);
  size_t o_dinv  = alloc((size_t)n * 4);      // memset region ends here
  size_t o_rp    = alloc((size_t)(n + 1) * 4);
  size_t o_bs    = alloc(4096 * 4);
  size_t o_w1fh  = alloc((size_t)KPAD * NHID * 2);
  size_t o_w1fl  = alloc((size_t)KPAD * NHID * 2);
  size_t o_w2f   = alloc((size_t)NHID * NCLS * 2);
  size_t o_ecw   = alloc((size_t)E * 8);
  size_t o_bufH  = alloc((size_t)n * NCLS * 2);
  size_t o_bufA  = alloc((size_t)n * NCLS * 2);
  size_t o_bufB  = alloc((size_t)n * NCLS * 2);

  int*   deg    = (int*)(w + o_deg);
  int*   cnt    = (int*)(w + o_cnt);
  int*   curi   = (int*)(w + o_cur);
  float* dinv   = (float*)(w + o_dinv);
  int*   rowptr = (int*)(w + o_rp);
  int*   bsums  = (int*)(w + o_bs);
  unsigned short* W1Fh = (unsigned short*)(w + o_w1fh);
  unsigned short* W1Fl = (unsigned short*)(w + o_w1fl);
  unsigned short* W2F  = (unsigned short*)(w + o_w2f);
  int2*  ecw    = (int2*)(w + o_ecw);
  unsigned short* bufH = (unsigned short*)(w + o_bufH);
  unsigned short* bufA = (unsigned short*)(w + o_bufA);
  unsigned short* bufB = (unsigned short*)(w + o_bufB);

  hipMemsetAsync(w + o_deg, 0, o_dinv - o_deg, stream);

  const int nb = (n + 255) / 256;

  conv_w1f<<<(KPAD * NHID + 255) / 256, 256, 0, stream>>>(W1, W1Fh, W1Fl);
  conv_w2f<<<(NHID * NCLS + 255) / 256, 256, 0, stream>>>(W2, W2F);

  edge_count<<<1024, 256, 0, stream>>>(ei, E, deg, cnt);
  make_dinv<<<nb, 256, 0, stream>>>(deg, dinv, n);
  scan_block<<<nb, 256, 0, stream>>>(cnt, rowptr, bsums, n);
  scan_sums<<<1, 1, 0, stream>>>(bsums, nb, rowptr);
  scan_add<<<nb, 256, 0, stream>>>(rowptr, bsums, n);
  scatter_edges<<<1024, 256, 0, stream>>>(ei, E, dinv, rowptr, curi, ecw);

  mlp_mfma<<<(n + 63) / 64, 256, 0, stream>>>(x, W1Fh, W1Fl, W2F, bufH, n);

  // 2 rows per wave, 4 waves per block
  const int waves = (n + 1) / 2;
  const int spmm_blocks = (waves + 3) / 4;
  spmm_first<<<spmm_blocks, 256, 0, stream>>>(rowptr, ecw, bufH, bufA, out, cw, n);

  unsigned short* P = bufH;
  unsigned short* C = bufA;
  unsigned short* N = bufB;
  for (int k = 2; k <= KPOLY; ++k) {
    spmm_step<<<spmm_blocks, 256, 0, stream>>>(rowptr, ecw, C, P, N, out, cw, k,
                                               (k == KPOLY) ? 1 : 0, n);
    unsigned short* t = P; P = C; C = N; N = t;
  }
}